// Round 5
// baseline (210.992 us; speedup 1.0000x reference)
//
#include <hip/hip_runtime.h>
#include <hip/hip_bf16.h>

#define NPIX 65536
#define NRAYS 65536
#define SS 48
#define NC 256
#define ND 16
#define DIST_BLOCKS (NRAYS/4)   // 4 rays (waves) per 256-thread block

// ---------------------------------------------------------------------------
// Front kernel: blocks [0,nblkA) do pixel pass A (rgb, opac, class count/sum,
// norm partials); blocks [nblkA, nblkA+DIST_BLOCKS) do distortion loss with
// one WAVE per ray (lane = sample; coalesced loads + shuffle prefix scan).
// ---------------------------------------------------------------------------
__global__ __launch_bounds__(256) void kFront(
    const float* __restrict__ rgb_pred, const float* __restrict__ rgb_gt,
    const float* __restrict__ opacity, const int* __restrict__ sam,
    const float* __restrict__ semantic,
    const float* __restrict__ wsv, const float* __restrict__ deltas,
    const float* __restrict__ tsv, const int* __restrict__ rays_a,
    float* __restrict__ o_rgb, float* __restrict__ o_opac,
    float* __restrict__ o_dist,
    float* __restrict__ cntpart, float* __restrict__ usumpart,
    float* __restrict__ scal, int nblkA, int ppbA)
{
    __shared__ float cnt_s[NC];
    __shared__ float us_s[NC*ND];
    __shared__ float red_s[8];
    const int t = threadIdx.x;

    if ((int)blockIdx.x < nblkA) {
        // ---------------- pixel pass A ----------------
        const int b = blockIdx.x;
        for (int j = t; j < NC; j += 256) cnt_s[j] = 0.f;
        for (int j = t; j < NC*ND; j += 256) us_s[j] = 0.f;
        __syncthreads();
        float nloc = 0.f, wloc = 0.f;
        for (int p = 0; p < ppbA; ++p) {
            const int i = (b*ppbA + p)*256 + t;
            const float pr0 = rgb_pred[3*i+0], pr1 = rgb_pred[3*i+1], pr2 = rgb_pred[3*i+2];
            const float g0 = rgb_gt[3*i+0],  g1 = rgb_gt[3*i+1],  g2 = rgb_gt[3*i+2];
            const float d0 = pr0-g0, d1 = pr1-g1, d2 = pr2-g2;
            o_rgb[3*i+0] = d0*d0; o_rgb[3*i+1] = d1*d1; o_rgb[3*i+2] = d2*d2;
            const float o = opacity[i] + 1e-10f;
            o_opac[i] = -0.001f * o * logf(o);
            const float4* sp = (const float4*)(semantic + (size_t)i*ND);
            const float4 a0 = sp[0], a1 = sp[1], a2 = sp[2], a3 = sp[3];
            const int seg = sam[i];
            if (seg > 0) {
                const int cl = seg - 1;
                const float ss =
                    a0.x*a0.x + a0.y*a0.y + a0.z*a0.z + a0.w*a0.w +
                    a1.x*a1.x + a1.y*a1.y + a1.z*a1.z + a1.w*a1.w +
                    a2.x*a2.x + a2.y*a2.y + a2.z*a2.z + a2.w*a2.w +
                    a3.x*a3.x + a3.y*a3.y + a3.z*a3.z + a3.w*a3.w;
                const float dn = sqrtf(ss) - 1.f;
                nloc += dn*dn; wloc += 1.f;
                atomicAdd(&cnt_s[cl], 1.f);
                float* up = us_s + cl*ND;
                atomicAdd(up+0,  a0.x); atomicAdd(up+1,  a0.y);
                atomicAdd(up+2,  a0.z); atomicAdd(up+3,  a0.w);
                atomicAdd(up+4,  a1.x); atomicAdd(up+5,  a1.y);
                atomicAdd(up+6,  a1.z); atomicAdd(up+7,  a1.w);
                atomicAdd(up+8,  a2.x); atomicAdd(up+9,  a2.y);
                atomicAdd(up+10, a2.z); atomicAdd(up+11, a2.w);
                atomicAdd(up+12, a3.x); atomicAdd(up+13, a3.y);
                atomicAdd(up+14, a3.z); atomicAdd(up+15, a3.w);
            }
        }
        __syncthreads();
        for (int j = t; j < NC; j += 256) cntpart[b*NC + j] = cnt_s[j];
        for (int j = t; j < NC*ND; j += 256) usumpart[(size_t)b*NC*ND + j] = us_s[j];
        for (int off = 32; off > 0; off >>= 1) {
            nloc += __shfl_down(nloc, off);
            wloc += __shfl_down(wloc, off);
        }
        if ((t & 63) == 0) { red_s[t>>6] = nloc; red_s[4 + (t>>6)] = wloc; }
        __syncthreads();
        if (t == 0) {
            atomicAdd(&scal[0], red_s[0]+red_s[1]+red_s[2]+red_s[3]);
            atomicAdd(&scal[1], red_s[4]+red_s[5]+red_s[6]+red_s[7]);
        }
    } else {
        // ---------------- distortion: one wave per ray ----------------
        const int bD = blockIdx.x - nblkA;
        const int lane = t & 63;
        const int ray = bD*4 + (t >> 6);
        const int start = rays_a[3*ray + 1];
        const int cnt   = rays_a[3*ray + 2];
        const bool act = lane < cnt;
        const float w_ = act ? wsv[start+lane]    : 0.f;
        const float t_ = act ? tsv[start+lane]    : 0.f;
        const float d_ = act ? deltas[start+lane] : 0.f;
        const float wt_ = w_*t_;
        float sw = w_, swt = wt_;
#pragma unroll
        for (int off = 1; off < 64; off <<= 1) {
            const float aw  = __shfl_up(sw, off);
            const float awt = __shfl_up(swt, off);
            if (lane >= off) { sw += aw; swt += awt; }
        }
        const float Wex = sw - w_, WTex = swt - wt_;
        float per = 2.f*w_*(t_*Wex - WTex) + w_*w_*d_*(1.f/3.f);
#pragma unroll
        for (int off = 32; off > 0; off >>= 1) per += __shfl_xor(per, off);
        if (lane == 0) o_dist[ray] = 0.001f * per;
    }
}

// Reduce per-block partials -> counts and class means u.
__global__ __launch_bounds__(256) void kP1(
    const float* __restrict__ cntpart, const float* __restrict__ usumpart,
    float* __restrict__ cnt, float* __restrict__ u, int nblkA)
{
    const int id = blockIdx.x*256 + threadIdx.x;   // 0..4095 = (c,k)
    const int c = id >> 4;
    float cs = 0.f, us = 0.f;
    for (int b = 0; b < nblkA; ++b) {
        cs += cntpart[b*NC + c];
        us += usumpart[(size_t)b*NC*ND + id];
    }
    const float csafe = fmaxf(cs, 1.f);
    u[id] = us / csafe;
    if ((id & 15) == 0) cnt[c] = cs;
}

// Deviation pass: sum ||sem_i - u[cl_i]|| per class (per-block partials).
__global__ __launch_bounds__(256) void kC(
    const float* __restrict__ semantic, const int* __restrict__ sam,
    const float* __restrict__ u, float* __restrict__ devpart, int ppb)
{
    __shared__ float u_s[NC*ND];
    __shared__ float dev_s[NC];
    const int t = threadIdx.x, b = blockIdx.x;
    for (int j = t; j < NC*ND; j += 256) u_s[j] = u[j];
    for (int j = t; j < NC; j += 256) dev_s[j] = 0.f;
    __syncthreads();
    for (int p = 0; p < ppb; ++p) {
        const int i = (b*ppb + p)*256 + t;
        const int seg = sam[i];
        if (seg > 0) {
            const int cl = seg - 1;
            const float4* sp = (const float4*)(semantic + (size_t)i*ND);
            const float4 a0 = sp[0], a1 = sp[1], a2 = sp[2], a3 = sp[3];
            const float4* up = (const float4*)(u_s + cl*ND);
            const float4 u0 = up[0], u1 = up[1], u2 = up[2], u3 = up[3];
            float q, d2 = 0.f;
            q = a0.x-u0.x; d2 += q*q;  q = a0.y-u0.y; d2 += q*q;
            q = a0.z-u0.z; d2 += q*q;  q = a0.w-u0.w; d2 += q*q;
            q = a1.x-u1.x; d2 += q*q;  q = a1.y-u1.y; d2 += q*q;
            q = a1.z-u1.z; d2 += q*q;  q = a1.w-u1.w; d2 += q*q;
            q = a2.x-u2.x; d2 += q*q;  q = a2.y-u2.y; d2 += q*q;
            q = a2.z-u2.z; d2 += q*q;  q = a2.w-u2.w; d2 += q*q;
            q = a3.x-u3.x; d2 += q*q;  q = a3.y-u3.y; d2 += q*q;
            q = a3.z-u3.z; d2 += q*q;  q = a3.w-u3.w; d2 += q*q;
            atomicAdd(&dev_s[cl], sqrtf(d2));
        }
    }
    __syncthreads();
    for (int j = t; j < NC; j += 256) devpart[b*NC + j] = dev_s[j];
}

// Reduce dev partials -> phi; emit uphi = u/phi and validity multiplier m.
__global__ __launch_bounds__(256) void kP2(
    const float* __restrict__ devpart, const float* __restrict__ cnt,
    const float* __restrict__ u, float* __restrict__ uphi,
    float* __restrict__ m, int nblkC)
{
    const int c = threadIdx.x;  // one block of 256
    float dv = 0.f;
    for (int b = 0; b < nblkC; ++b) dv += devpart[b*NC + c];
    const float cs = cnt[c];
    const float csafe = fmaxf(cs, 1.f);
    const float phiraw = dv / (csafe * logf(cs + 10.f));
    const float phi = fminf(fmaxf(phiraw * 10.f, 0.1f), 1.f);
    const float inv = 1.f / phi;
    m[c] = (cs > 2.0f) ? 1.f : 0.f;
    for (int k = 0; k < ND; ++k) uphi[c*ND + k] = u[c*ND + k] * inv;
}

// NCE pass: block = 64 pixels; wave w owns class chunk [w*64, w*64+64).
// Class address is wave-uniform -> LDS broadcast reads, no conflicts.
__global__ __launch_bounds__(256) void kD(
    const float* __restrict__ semantic, const int* __restrict__ sam,
    const float* __restrict__ uphi, const float* __restrict__ m,
    float* __restrict__ scal, float* __restrict__ o_sem)
{
    __shared__ float uphi_s[NC*ND];     // 16 KB
    __shared__ float m_s[NC];
    __shared__ float part_d[4][64];
    __shared__ float part_l[4][64];
    const int t = threadIdx.x;
    const int w = t >> 6, lane = t & 63;

    {   // cooperative stage: uphi (1024 float4) + m
        const float4* g = (const float4*)uphi;
        float4* s = (float4*)uphi_s;
#pragma unroll
        for (int j = 0; j < 4; ++j) s[t + 256*j] = g[t + 256*j];
        m_s[t] = m[t];
    }
    const int i = blockIdx.x*64 + lane;          // this wave's pixel for lane
    const float4* sp = (const float4*)(semantic + (size_t)i*ND);
    const float4 a0 = sp[0], a1 = sp[1], a2 = sp[2], a3 = sp[3];
    const int seg = sam[i];
    const int cl = (seg > 0) ? (seg - 1) : 0;
    __syncthreads();

    float denom = 0.f, lcl = 0.f;
#pragma unroll 4
    for (int j = 0; j < 64; ++j) {
        const int c = w*64 + j;                  // uniform across the wave
        const float4* up = (const float4*)(uphi_s + c*ND);
        const float4 u0 = up[0], u1 = up[1], u2 = up[2], u3 = up[3];
        const float dotv =
            a0.x*u0.x + a0.y*u0.y + a0.z*u0.z + a0.w*u0.w +
            a1.x*u1.x + a1.y*u1.y + a1.z*u1.z + a1.w*u1.w +
            a2.x*u2.x + a2.y*u2.y + a2.z*u2.z + a2.w*u2.w +
            a3.x*u3.x + a3.y*u3.y + a3.z*u3.z + a3.w*u3.w;
        denom += m_s[c] * __expf(dotv);
        if (c == cl) lcl = dotv;
    }
    part_d[w][lane] = denom;
    part_l[w][lane] = lcl;
    __syncthreads();

    if (w == 0) {
        float dtot = part_d[0][lane] + part_d[1][lane] + part_d[2][lane] + part_d[3][lane] + 1e-6f;
        float ltot = part_l[0][lane] + part_l[1][lane] + part_l[2][lane] + part_l[3][lane];
        float contrib = (seg > 0 && m_s[cl] > 0.5f) ? (__logf(dtot) - ltot) : 0.f;
#pragma unroll
        for (int off = 32; off > 0; off >>= 1) contrib += __shfl_xor(contrib, off);
        if (lane == 0) atomicAdd(&scal[2], contrib);
    }
    // last-block finalize (replaces kE)
    if (t == 0) {
        __threadfence();
        unsigned* done = (unsigned*)(scal + 3);
        const unsigned old = atomicAdd(done, 1u);
        if (old == gridDim.x - 1) {
            const float proto = atomicAdd(&scal[2], 0.f);
            const float nrm   = atomicAdd(&scal[0], 0.f);
            const float wsum  = atomicAdd(&scal[1], 0.f);
            o_sem[0] = 1e-4f * proto + 100.f * nrm / fmaxf(wsum, 1.f);
        }
    }
}

extern "C" void kernel_launch(void* const* d_in, const int* in_sizes, int n_in,
                              void* d_out, int out_size, void* d_ws, size_t ws_size,
                              hipStream_t stream)
{
    const float* rgb_pred = (const float*)d_in[0];
    const float* rgb_gt   = (const float*)d_in[1];
    const float* opacity  = (const float*)d_in[2];
    const float* wsv      = (const float*)d_in[3];
    const float* deltas   = (const float*)d_in[4];
    const float* tsv      = (const float*)d_in[5];
    const int*   rays_a   = (const int*)d_in[6];
    const int*   sam      = (const int*)d_in[7];
    const float* semantic = (const float*)d_in[8];

    float* out    = (float*)d_out;
    float* o_rgb  = out;                 // 196608
    float* o_opac = out + 196608;        // 65536
    float* o_dist = out + 262144;        // 65536
    float* o_sem  = out + 327680;        // 1
    float* wsf    = (float*)d_ws;

    // choose partial-block counts by available workspace (deterministic)
    int nblkA = 256, nblkC = 256;
    size_t need = ((size_t)nblkA*NC*(ND+1) + (size_t)nblkC*NC + NC*(2*ND+2) + 8) * 4;
    if (ws_size < need) { nblkA = 128; nblkC = 128; }
    const int ppbA = NPIX / (nblkA * 256);
    const int ppbC = NPIX / (nblkC * 256);

    float* w_cntpart = wsf;
    float* w_usum    = w_cntpart + (size_t)nblkA*NC;
    float* w_devpart = w_usum + (size_t)nblkA*NC*ND;
    float* w_cnt     = w_devpart + (size_t)nblkC*NC;
    float* w_u       = w_cnt + NC;
    float* w_uphi    = w_u + NC*ND;
    float* w_m       = w_uphi + NC*ND;
    float* w_scal    = w_m + NC;      // [0]=norm [1]=wsum [2]=proto [3]=done-counter

    hipMemsetAsync(w_scal, 0, 4*sizeof(float), stream);

    kFront<<<nblkA + DIST_BLOCKS, 256, 0, stream>>>(
        rgb_pred, rgb_gt, opacity, sam, semantic,
        wsv, deltas, tsv, rays_a,
        o_rgb, o_opac, o_dist,
        w_cntpart, w_usum, w_scal, nblkA, ppbA);
    kP1<<<(NC*ND)/256, 256, 0, stream>>>(w_cntpart, w_usum, w_cnt, w_u, nblkA);
    kC<<<nblkC, 256, 0, stream>>>(semantic, sam, w_u, w_devpart, ppbC);
    kP2<<<1, 256, 0, stream>>>(w_devpart, w_cnt, w_u, w_uphi, w_m, nblkC);
    kD<<<NPIX/64, 256, 0, stream>>>(semantic, sam, w_uphi, w_m, w_scal, o_sem);
}

// Round 6
// 90.424 us; speedup vs baseline: 2.3334x; 2.3334x over previous
//
#include <hip/hip_runtime.h>
#include <hip/hip_bf16.h>

#define NPIX 65536
#define NRAYS 65536
#define SS 48
#define NC 256
#define ND 16
#define DIST_BLOCKS (NRAYS/4)   // 4 rays (waves) per 256-thread block

// ---------------------------------------------------------------------------
// Front kernel: blocks [0,nblkA) do pixel pass A (rgb, opac, class count/sum,
// norm partials); blocks [nblkA, nblkA+DIST_BLOCKS) do distortion loss with
// one WAVE per ray (lane = sample; coalesced loads + shuffle prefix scan).
// ---------------------------------------------------------------------------
__global__ __launch_bounds__(256) void kFront(
    const float* __restrict__ rgb_pred, const float* __restrict__ rgb_gt,
    const float* __restrict__ opacity, const int* __restrict__ sam,
    const float* __restrict__ semantic,
    const float* __restrict__ wsv, const float* __restrict__ deltas,
    const float* __restrict__ tsv, const int* __restrict__ rays_a,
    float* __restrict__ o_rgb, float* __restrict__ o_opac,
    float* __restrict__ o_dist,
    float* __restrict__ cntpart, float* __restrict__ usumpart,
    float* __restrict__ scal, int nblkA, int ppbA)
{
    __shared__ float cnt_s[NC];
    __shared__ float us_s[NC*ND];
    __shared__ float red_s[8];
    const int t = threadIdx.x;

    if ((int)blockIdx.x < nblkA) {
        // ---------------- pixel pass A ----------------
        const int b = blockIdx.x;
        for (int j = t; j < NC; j += 256) cnt_s[j] = 0.f;
        for (int j = t; j < NC*ND; j += 256) us_s[j] = 0.f;
        __syncthreads();
        float nloc = 0.f, wloc = 0.f;
        for (int p = 0; p < ppbA; ++p) {
            const int i = (b*ppbA + p)*256 + t;
            const float pr0 = rgb_pred[3*i+0], pr1 = rgb_pred[3*i+1], pr2 = rgb_pred[3*i+2];
            const float g0 = rgb_gt[3*i+0],  g1 = rgb_gt[3*i+1],  g2 = rgb_gt[3*i+2];
            const float d0 = pr0-g0, d1 = pr1-g1, d2 = pr2-g2;
            o_rgb[3*i+0] = d0*d0; o_rgb[3*i+1] = d1*d1; o_rgb[3*i+2] = d2*d2;
            const float o = opacity[i] + 1e-10f;
            o_opac[i] = -0.001f * o * logf(o);
            const float4* sp = (const float4*)(semantic + (size_t)i*ND);
            const float4 a0 = sp[0], a1 = sp[1], a2 = sp[2], a3 = sp[3];
            const int seg = sam[i];
            if (seg > 0) {
                const int cl = seg - 1;
                const float ss =
                    a0.x*a0.x + a0.y*a0.y + a0.z*a0.z + a0.w*a0.w +
                    a1.x*a1.x + a1.y*a1.y + a1.z*a1.z + a1.w*a1.w +
                    a2.x*a2.x + a2.y*a2.y + a2.z*a2.z + a2.w*a2.w +
                    a3.x*a3.x + a3.y*a3.y + a3.z*a3.z + a3.w*a3.w;
                const float dn = sqrtf(ss) - 1.f;
                nloc += dn*dn; wloc += 1.f;
                atomicAdd(&cnt_s[cl], 1.f);
                float* up = us_s + cl*ND;
                atomicAdd(up+0,  a0.x); atomicAdd(up+1,  a0.y);
                atomicAdd(up+2,  a0.z); atomicAdd(up+3,  a0.w);
                atomicAdd(up+4,  a1.x); atomicAdd(up+5,  a1.y);
                atomicAdd(up+6,  a1.z); atomicAdd(up+7,  a1.w);
                atomicAdd(up+8,  a2.x); atomicAdd(up+9,  a2.y);
                atomicAdd(up+10, a2.z); atomicAdd(up+11, a2.w);
                atomicAdd(up+12, a3.x); atomicAdd(up+13, a3.y);
                atomicAdd(up+14, a3.z); atomicAdd(up+15, a3.w);
            }
        }
        __syncthreads();
        for (int j = t; j < NC; j += 256) cntpart[b*NC + j] = cnt_s[j];
        for (int j = t; j < NC*ND; j += 256) usumpart[(size_t)b*NC*ND + j] = us_s[j];
        for (int off = 32; off > 0; off >>= 1) {
            nloc += __shfl_down(nloc, off);
            wloc += __shfl_down(wloc, off);
        }
        if ((t & 63) == 0) { red_s[t>>6] = nloc; red_s[4 + (t>>6)] = wloc; }
        __syncthreads();
        if (t == 0) {
            atomicAdd(&scal[0], red_s[0]+red_s[1]+red_s[2]+red_s[3]);
            atomicAdd(&scal[1], red_s[4]+red_s[5]+red_s[6]+red_s[7]);
        }
    } else {
        // ---------------- distortion: one wave per ray ----------------
        const int bD = blockIdx.x - nblkA;
        const int lane = t & 63;
        const int ray = bD*4 + (t >> 6);
        const int start = rays_a[3*ray + 1];
        const int cnt   = rays_a[3*ray + 2];
        const bool act = lane < cnt;
        const float w_ = act ? wsv[start+lane]    : 0.f;
        const float t_ = act ? tsv[start+lane]    : 0.f;
        const float d_ = act ? deltas[start+lane] : 0.f;
        const float wt_ = w_*t_;
        float sw = w_, swt = wt_;
#pragma unroll
        for (int off = 1; off < 64; off <<= 1) {
            const float aw  = __shfl_up(sw, off);
            const float awt = __shfl_up(swt, off);
            if (lane >= off) { sw += aw; swt += awt; }
        }
        const float Wex = sw - w_, WTex = swt - wt_;
        float per = 2.f*w_*(t_*Wex - WTex) + w_*w_*d_*(1.f/3.f);
#pragma unroll
        for (int off = 32; off > 0; off >>= 1) per += __shfl_xor(per, off);
        if (lane == 0) o_dist[ray] = 0.001f * per;
    }
}

// Reduce per-block partials -> counts and class means u.
// One block PER CLASS: 256 threads = 16 dims x 16 b-stripes (parallel loads),
// plus a full-block shuffle reduce for the count column.
__global__ __launch_bounds__(256) void kP1(
    const float* __restrict__ cntpart, const float* __restrict__ usumpart,
    float* __restrict__ cnt, float* __restrict__ u, int nblkA)
{
    const int c = blockIdx.x;          // class
    const int t = threadIdx.x;
    const int kk = t & 15;             // dim
    const int s  = t >> 4;             // b-stripe 0..15

    float us = 0.f;
    for (int b = s; b < nblkA; b += 16)
        us += usumpart[(size_t)b*(NC*ND) + c*ND + kk];

    __shared__ float lds[16][17];
    lds[s][kk] = us;

    float cs = (t < nblkA) ? cntpart[t*NC + c] : 0.f;
#pragma unroll
    for (int off = 32; off > 0; off >>= 1) cs += __shfl_xor(cs, off);
    __shared__ float cred[4];
    if ((t & 63) == 0) cred[t >> 6] = cs;
    __syncthreads();

    if (t < 16) {
        const float ctot = cred[0]+cred[1]+cred[2]+cred[3];
        float tot = 0.f;
#pragma unroll
        for (int s2 = 0; s2 < 16; ++s2) tot += lds[s2][t];
        u[c*ND + t] = tot / fmaxf(ctot, 1.f);
        if (t == 0) cnt[c] = ctot;
    }
}

// Deviation pass: sum ||sem_i - u[cl_i]|| per class (per-block partials).
__global__ __launch_bounds__(256) void kC(
    const float* __restrict__ semantic, const int* __restrict__ sam,
    const float* __restrict__ u, float* __restrict__ devpart, int ppb)
{
    __shared__ float u_s[NC*ND];
    __shared__ float dev_s[NC];
    const int t = threadIdx.x, b = blockIdx.x;
    for (int j = t; j < NC*ND; j += 256) u_s[j] = u[j];
    for (int j = t; j < NC; j += 256) dev_s[j] = 0.f;
    __syncthreads();
    for (int p = 0; p < ppb; ++p) {
        const int i = (b*ppb + p)*256 + t;
        const int seg = sam[i];
        if (seg > 0) {
            const int cl = seg - 1;
            const float4* sp = (const float4*)(semantic + (size_t)i*ND);
            const float4 a0 = sp[0], a1 = sp[1], a2 = sp[2], a3 = sp[3];
            const float4* up = (const float4*)(u_s + cl*ND);
            const float4 u0 = up[0], u1 = up[1], u2 = up[2], u3 = up[3];
            float q, d2 = 0.f;
            q = a0.x-u0.x; d2 += q*q;  q = a0.y-u0.y; d2 += q*q;
            q = a0.z-u0.z; d2 += q*q;  q = a0.w-u0.w; d2 += q*q;
            q = a1.x-u1.x; d2 += q*q;  q = a1.y-u1.y; d2 += q*q;
            q = a1.z-u1.z; d2 += q*q;  q = a1.w-u1.w; d2 += q*q;
            q = a2.x-u2.x; d2 += q*q;  q = a2.y-u2.y; d2 += q*q;
            q = a2.z-u2.z; d2 += q*q;  q = a2.w-u2.w; d2 += q*q;
            q = a3.x-u3.x; d2 += q*q;  q = a3.y-u3.y; d2 += q*q;
            q = a3.z-u3.z; d2 += q*q;  q = a3.w-u3.w; d2 += q*q;
            atomicAdd(&dev_s[cl], sqrtf(d2));
        }
    }
    __syncthreads();
    for (int j = t; j < NC; j += 256) devpart[b*NC + j] = dev_s[j];
}

// Reduce dev partials -> phi; emit uphi = u/phi and validity multiplier m.
// One block PER CLASS (parallel column reduce).
__global__ __launch_bounds__(256) void kP2(
    const float* __restrict__ devpart, const float* __restrict__ cnt,
    const float* __restrict__ u, float* __restrict__ uphi,
    float* __restrict__ m, int nblkC)
{
    const int c = blockIdx.x;
    const int t = threadIdx.x;

    float dv = (t < nblkC) ? devpart[t*NC + c] : 0.f;
#pragma unroll
    for (int off = 32; off > 0; off >>= 1) dv += __shfl_xor(dv, off);
    __shared__ float dred[4];
    __shared__ float inv_s;
    if ((t & 63) == 0) dred[t >> 6] = dv;
    __syncthreads();

    if (t == 0) {
        const float dtot = dred[0]+dred[1]+dred[2]+dred[3];
        const float cs = cnt[c];
        const float csafe = fmaxf(cs, 1.f);
        const float phiraw = dtot / (csafe * logf(cs + 10.f));
        const float phi = fminf(fmaxf(phiraw * 10.f, 0.1f), 1.f);
        inv_s = 1.f / phi;
        m[c] = (cs > 2.0f) ? 1.f : 0.f;
    }
    __syncthreads();
    if (t < 16) uphi[c*ND + t] = u[c*ND + t] * inv_s;
}

// NCE pass: block = 64 pixels; wave w owns class chunk [w*64, w*64+64).
// Class address is wave-uniform -> LDS broadcast reads, no conflicts.
__global__ __launch_bounds__(256) void kD(
    const float* __restrict__ semantic, const int* __restrict__ sam,
    const float* __restrict__ uphi, const float* __restrict__ m,
    float* __restrict__ scal, float* __restrict__ o_sem)
{
    __shared__ float uphi_s[NC*ND];     // 16 KB
    __shared__ float m_s[NC];
    __shared__ float part_d[4][64];
    __shared__ float part_l[4][64];
    const int t = threadIdx.x;
    const int w = t >> 6, lane = t & 63;

    {   // cooperative stage: uphi (1024 float4) + m
        const float4* g = (const float4*)uphi;
        float4* s = (float4*)uphi_s;
#pragma unroll
        for (int j = 0; j < 4; ++j) s[t + 256*j] = g[t + 256*j];
        m_s[t] = m[t];
    }
    const int i = blockIdx.x*64 + lane;          // this wave's pixel for lane
    const float4* sp = (const float4*)(semantic + (size_t)i*ND);
    const float4 a0 = sp[0], a1 = sp[1], a2 = sp[2], a3 = sp[3];
    const int seg = sam[i];
    const int cl = (seg > 0) ? (seg - 1) : 0;
    __syncthreads();

    float denom = 0.f, lcl = 0.f;
#pragma unroll 4
    for (int j = 0; j < 64; ++j) {
        const int c = w*64 + j;                  // uniform across the wave
        const float4* up = (const float4*)(uphi_s + c*ND);
        const float4 u0 = up[0], u1 = up[1], u2 = up[2], u3 = up[3];
        const float dotv =
            a0.x*u0.x + a0.y*u0.y + a0.z*u0.z + a0.w*u0.w +
            a1.x*u1.x + a1.y*u1.y + a1.z*u1.z + a1.w*u1.w +
            a2.x*u2.x + a2.y*u2.y + a2.z*u2.z + a2.w*u2.w +
            a3.x*u3.x + a3.y*u3.y + a3.z*u3.z + a3.w*u3.w;
        denom += m_s[c] * __expf(dotv);
        if (c == cl) lcl = dotv;
    }
    part_d[w][lane] = denom;
    part_l[w][lane] = lcl;
    __syncthreads();

    if (w == 0) {
        float dtot = part_d[0][lane] + part_d[1][lane] + part_d[2][lane] + part_d[3][lane] + 1e-6f;
        float ltot = part_l[0][lane] + part_l[1][lane] + part_l[2][lane] + part_l[3][lane];
        float contrib = (seg > 0 && m_s[cl] > 0.5f) ? (__logf(dtot) - ltot) : 0.f;
#pragma unroll
        for (int off = 32; off > 0; off >>= 1) contrib += __shfl_xor(contrib, off);
        if (lane == 0) atomicAdd(&scal[2], contrib);
    }
    // last-block finalize (replaces kE)
    if (t == 0) {
        __threadfence();
        unsigned* done = (unsigned*)(scal + 3);
        const unsigned old = atomicAdd(done, 1u);
        if (old == gridDim.x - 1) {
            const float proto = atomicAdd(&scal[2], 0.f);
            const float nrm   = atomicAdd(&scal[0], 0.f);
            const float wsum  = atomicAdd(&scal[1], 0.f);
            o_sem[0] = 1e-4f * proto + 100.f * nrm / fmaxf(wsum, 1.f);
        }
    }
}

extern "C" void kernel_launch(void* const* d_in, const int* in_sizes, int n_in,
                              void* d_out, int out_size, void* d_ws, size_t ws_size,
                              hipStream_t stream)
{
    const float* rgb_pred = (const float*)d_in[0];
    const float* rgb_gt   = (const float*)d_in[1];
    const float* opacity  = (const float*)d_in[2];
    const float* wsv      = (const float*)d_in[3];
    const float* deltas   = (const float*)d_in[4];
    const float* tsv      = (const float*)d_in[5];
    const int*   rays_a   = (const int*)d_in[6];
    const int*   sam      = (const int*)d_in[7];
    const float* semantic = (const float*)d_in[8];

    float* out    = (float*)d_out;
    float* o_rgb  = out;                 // 196608
    float* o_opac = out + 196608;        // 65536
    float* o_dist = out + 262144;        // 65536
    float* o_sem  = out + 327680;        // 1
    float* wsf    = (float*)d_ws;

    // choose partial-block counts by available workspace (deterministic)
    int nblkA = 256, nblkC = 256;
    size_t need = ((size_t)nblkA*NC*(ND+1) + (size_t)nblkC*NC + NC*(2*ND+2) + 8) * 4;
    if (ws_size < need) { nblkA = 128; nblkC = 128; }
    const int ppbA = NPIX / (nblkA * 256);
    const int ppbC = NPIX / (nblkC * 256);

    float* w_cntpart = wsf;
    float* w_usum    = w_cntpart + (size_t)nblkA*NC;
    float* w_devpart = w_usum + (size_t)nblkA*NC*ND;
    float* w_cnt     = w_devpart + (size_t)nblkC*NC;
    float* w_u       = w_cnt + NC;
    float* w_uphi    = w_u + NC*ND;
    float* w_m       = w_uphi + NC*ND;
    float* w_scal    = w_m + NC;      // [0]=norm [1]=wsum [2]=proto [3]=done-counter

    hipMemsetAsync(w_scal, 0, 4*sizeof(float), stream);

    kFront<<<nblkA + DIST_BLOCKS, 256, 0, stream>>>(
        rgb_pred, rgb_gt, opacity, sam, semantic,
        wsv, deltas, tsv, rays_a,
        o_rgb, o_opac, o_dist,
        w_cntpart, w_usum, w_scal, nblkA, ppbA);
    kP1<<<NC, 256, 0, stream>>>(w_cntpart, w_usum, w_cnt, w_u, nblkA);
    kC<<<nblkC, 256, 0, stream>>>(semantic, sam, w_u, w_devpart, ppbC);
    kP2<<<NC, 256, 0, stream>>>(w_devpart, w_cnt, w_u, w_uphi, w_m, nblkC);
    kD<<<NPIX/64, 256, 0, stream>>>(semantic, sam, w_uphi, w_m, w_scal, o_sem);
}

// Round 7
// 78.423 us; speedup vs baseline: 2.6904x; 1.1530x over previous
//
#include <hip/hip_runtime.h>
#include <hip/hip_bf16.h>

#define NPIX 65536
#define NRAYS 65536
#define SS 48
#define NC 256
#define ND 16
#define DIST_BLOCKS (NRAYS/4)   // 4 rays (waves) per 256-thread block

// ---------------------------------------------------------------------------
// Front kernel: blocks [0,nblkA) do pixel pass A (rgb, opac, class count/sum,
// norm partials); blocks [nblkA, nblkA+DIST_BLOCKS) do distortion loss with
// one WAVE per ray (lane = sample; coalesced loads + shuffle prefix scan).
// ---------------------------------------------------------------------------
__global__ __launch_bounds__(256) void kFront(
    const float* __restrict__ rgb_pred, const float* __restrict__ rgb_gt,
    const float* __restrict__ opacity, const int* __restrict__ sam,
    const float* __restrict__ semantic,
    const float* __restrict__ wsv, const float* __restrict__ deltas,
    const float* __restrict__ tsv, const int* __restrict__ rays_a,
    float* __restrict__ o_rgb, float* __restrict__ o_opac,
    float* __restrict__ o_dist,
    float* __restrict__ cntpart, float* __restrict__ usumpart,
    float* __restrict__ scal, int nblkA, int ppbA)
{
    __shared__ float cnt_s[NC];
    __shared__ float us_s[NC*ND];
    __shared__ float red_s[8];
    const int t = threadIdx.x;

    if ((int)blockIdx.x < nblkA) {
        // ---------------- pixel pass A ----------------
        const int b = blockIdx.x;
        for (int j = t; j < NC; j += 256) cnt_s[j] = 0.f;
        for (int j = t; j < NC*ND; j += 256) us_s[j] = 0.f;
        __syncthreads();
        float nloc = 0.f, wloc = 0.f;
        for (int p = 0; p < ppbA; ++p) {
            const int i = (b*ppbA + p)*256 + t;
            const float pr0 = rgb_pred[3*i+0], pr1 = rgb_pred[3*i+1], pr2 = rgb_pred[3*i+2];
            const float g0 = rgb_gt[3*i+0],  g1 = rgb_gt[3*i+1],  g2 = rgb_gt[3*i+2];
            const float d0 = pr0-g0, d1 = pr1-g1, d2 = pr2-g2;
            o_rgb[3*i+0] = d0*d0; o_rgb[3*i+1] = d1*d1; o_rgb[3*i+2] = d2*d2;
            const float o = opacity[i] + 1e-10f;
            o_opac[i] = -0.001f * o * logf(o);
            const float4* sp = (const float4*)(semantic + (size_t)i*ND);
            const float4 a0 = sp[0], a1 = sp[1], a2 = sp[2], a3 = sp[3];
            const int seg = sam[i];
            if (seg > 0) {
                const int cl = seg - 1;
                const float ss =
                    a0.x*a0.x + a0.y*a0.y + a0.z*a0.z + a0.w*a0.w +
                    a1.x*a1.x + a1.y*a1.y + a1.z*a1.z + a1.w*a1.w +
                    a2.x*a2.x + a2.y*a2.y + a2.z*a2.z + a2.w*a2.w +
                    a3.x*a3.x + a3.y*a3.y + a3.z*a3.z + a3.w*a3.w;
                const float dn = sqrtf(ss) - 1.f;
                nloc += dn*dn; wloc += 1.f;
                atomicAdd(&cnt_s[cl], 1.f);
                float* up = us_s + cl*ND;
                atomicAdd(up+0,  a0.x); atomicAdd(up+1,  a0.y);
                atomicAdd(up+2,  a0.z); atomicAdd(up+3,  a0.w);
                atomicAdd(up+4,  a1.x); atomicAdd(up+5,  a1.y);
                atomicAdd(up+6,  a1.z); atomicAdd(up+7,  a1.w);
                atomicAdd(up+8,  a2.x); atomicAdd(up+9,  a2.y);
                atomicAdd(up+10, a2.z); atomicAdd(up+11, a2.w);
                atomicAdd(up+12, a3.x); atomicAdd(up+13, a3.y);
                atomicAdd(up+14, a3.z); atomicAdd(up+15, a3.w);
            }
        }
        __syncthreads();
        for (int j = t; j < NC; j += 256) cntpart[b*NC + j] = cnt_s[j];
        for (int j = t; j < NC*ND; j += 256) usumpart[(size_t)b*NC*ND + j] = us_s[j];
        for (int off = 32; off > 0; off >>= 1) {
            nloc += __shfl_down(nloc, off);
            wloc += __shfl_down(wloc, off);
        }
        if ((t & 63) == 0) { red_s[t>>6] = nloc; red_s[4 + (t>>6)] = wloc; }
        __syncthreads();
        if (t == 0) {
            atomicAdd(&scal[0], red_s[0]+red_s[1]+red_s[2]+red_s[3]);
            atomicAdd(&scal[1], red_s[4]+red_s[5]+red_s[6]+red_s[7]);
        }
    } else {
        // ---------------- distortion: one wave per ray ----------------
        const int bD = blockIdx.x - nblkA;
        const int lane = t & 63;
        const int ray = bD*4 + (t >> 6);
        const int start = rays_a[3*ray + 1];
        const int cnt   = rays_a[3*ray + 2];
        const bool act = lane < cnt;
        const float w_ = act ? wsv[start+lane]    : 0.f;
        const float t_ = act ? tsv[start+lane]    : 0.f;
        const float d_ = act ? deltas[start+lane] : 0.f;
        const float wt_ = w_*t_;
        float sw = w_, swt = wt_;
#pragma unroll
        for (int off = 1; off < 64; off <<= 1) {
            const float aw  = __shfl_up(sw, off);
            const float awt = __shfl_up(swt, off);
            if (lane >= off) { sw += aw; swt += awt; }
        }
        const float Wex = sw - w_, WTex = swt - wt_;
        float per = 2.f*w_*(t_*Wex - WTex) + w_*w_*d_*(1.f/3.f);
#pragma unroll
        for (int off = 32; off > 0; off >>= 1) per += __shfl_xor(per, off);
        if (lane == 0) o_dist[ray] = 0.001f * per;
    }
}

// Reduce per-block partials -> counts and class means u.
// One block PER CLASS: 256 threads = 16 dims x 16 b-stripes (parallel loads),
// plus a full-block shuffle reduce for the count column.
__global__ __launch_bounds__(256) void kP1(
    const float* __restrict__ cntpart, const float* __restrict__ usumpart,
    float* __restrict__ cnt, float* __restrict__ u, int nblkA)
{
    const int c = blockIdx.x;          // class
    const int t = threadIdx.x;
    const int kk = t & 15;             // dim
    const int s  = t >> 4;             // b-stripe 0..15

    float us = 0.f;
    for (int b = s; b < nblkA; b += 16)
        us += usumpart[(size_t)b*(NC*ND) + c*ND + kk];

    __shared__ float lds[16][17];
    lds[s][kk] = us;

    float cs = (t < nblkA) ? cntpart[t*NC + c] : 0.f;
#pragma unroll
    for (int off = 32; off > 0; off >>= 1) cs += __shfl_xor(cs, off);
    __shared__ float cred[4];
    if ((t & 63) == 0) cred[t >> 6] = cs;
    __syncthreads();

    if (t < 16) {
        const float ctot = cred[0]+cred[1]+cred[2]+cred[3];
        float tot = 0.f;
#pragma unroll
        for (int s2 = 0; s2 < 16; ++s2) tot += lds[s2][t];
        u[c*ND + t] = tot / fmaxf(ctot, 1.f);
        if (t == 0) cnt[c] = ctot;
    }
}

// Deviation pass: sum ||sem_i - u[cl_i]|| per class (per-block partials).
__global__ __launch_bounds__(256) void kC(
    const float* __restrict__ semantic, const int* __restrict__ sam,
    const float* __restrict__ u, float* __restrict__ devpart, int ppb)
{
    __shared__ float u_s[NC*ND];
    __shared__ float dev_s[NC];
    const int t = threadIdx.x, b = blockIdx.x;
    for (int j = t; j < NC*ND; j += 256) u_s[j] = u[j];
    for (int j = t; j < NC; j += 256) dev_s[j] = 0.f;
    __syncthreads();
    for (int p = 0; p < ppb; ++p) {
        const int i = (b*ppb + p)*256 + t;
        const int seg = sam[i];
        if (seg > 0) {
            const int cl = seg - 1;
            const float4* sp = (const float4*)(semantic + (size_t)i*ND);
            const float4 a0 = sp[0], a1 = sp[1], a2 = sp[2], a3 = sp[3];
            const float4* up = (const float4*)(u_s + cl*ND);
            const float4 u0 = up[0], u1 = up[1], u2 = up[2], u3 = up[3];
            float q, d2 = 0.f;
            q = a0.x-u0.x; d2 += q*q;  q = a0.y-u0.y; d2 += q*q;
            q = a0.z-u0.z; d2 += q*q;  q = a0.w-u0.w; d2 += q*q;
            q = a1.x-u1.x; d2 += q*q;  q = a1.y-u1.y; d2 += q*q;
            q = a1.z-u1.z; d2 += q*q;  q = a1.w-u1.w; d2 += q*q;
            q = a2.x-u2.x; d2 += q*q;  q = a2.y-u2.y; d2 += q*q;
            q = a2.z-u2.z; d2 += q*q;  q = a2.w-u2.w; d2 += q*q;
            q = a3.x-u3.x; d2 += q*q;  q = a3.y-u3.y; d2 += q*q;
            q = a3.z-u3.z; d2 += q*q;  q = a3.w-u3.w; d2 += q*q;
            atomicAdd(&dev_s[cl], sqrtf(d2));
        }
    }
    __syncthreads();
    for (int j = t; j < NC; j += 256) devpart[b*NC + j] = dev_s[j];
}

// Reduce dev partials -> phi; emit uphi = u/phi and validity multiplier m.
// One block PER CLASS (parallel column reduce).
__global__ __launch_bounds__(256) void kP2(
    const float* __restrict__ devpart, const float* __restrict__ cnt,
    const float* __restrict__ u, float* __restrict__ uphi,
    float* __restrict__ m, int nblkC)
{
    const int c = blockIdx.x;
    const int t = threadIdx.x;

    float dv = (t < nblkC) ? devpart[t*NC + c] : 0.f;
#pragma unroll
    for (int off = 32; off > 0; off >>= 1) dv += __shfl_xor(dv, off);
    __shared__ float dred[4];
    __shared__ float inv_s;
    if ((t & 63) == 0) dred[t >> 6] = dv;
    __syncthreads();

    if (t == 0) {
        const float dtot = dred[0]+dred[1]+dred[2]+dred[3];
        const float cs = cnt[c];
        const float csafe = fmaxf(cs, 1.f);
        const float phiraw = dtot / (csafe * logf(cs + 10.f));
        const float phi = fminf(fmaxf(phiraw * 10.f, 0.1f), 1.f);
        inv_s = 1.f / phi;
        m[c] = (cs > 2.0f) ? 1.f : 0.f;
    }
    __syncthreads();
    if (t < 16) uphi[c*ND + t] = u[c*ND + t] * inv_s;
}

// NCE pass: block = 128 pixels (2 per lane), 4 waves; wave w owns class chunk
// [w*64, w*64+64). u/phi is fetched via the SCALAR path (wave-uniform address
// forced with readfirstlane -> s_load_dwordx16): no LDS traffic, u in SGPRs.
__global__ __launch_bounds__(256) void kD(
    const float* __restrict__ semantic, const int* __restrict__ sam,
    const float* __restrict__ uphi, const float* __restrict__ m,
    float* __restrict__ scal, float* __restrict__ o_sem)
{
    __shared__ float part_d[4][128];
    __shared__ float red_s[4];
    const int t = threadIdx.x;
    const int lane = t & 63;
    const int w = __builtin_amdgcn_readfirstlane(t >> 6);   // uniform wave id

    const int base = blockIdx.x * 128;
    // 2 pixels per lane, coalesced: p0 = base+lane, p1 = base+64+lane
    const float4* sp0 = (const float4*)(semantic + (size_t)(base + lane)*ND);
    const float4* sp1 = (const float4*)(semantic + (size_t)(base + 64 + lane)*ND);
    const float4 a00 = sp0[0], a01 = sp0[1], a02 = sp0[2], a03 = sp0[3];
    const float4 a10 = sp1[0], a11 = sp1[1], a12 = sp1[2], a13 = sp1[3];

    float denom0 = 0.f, denom1 = 0.f;
#pragma unroll 4
    for (int j = 0; j < 64; ++j) {
        const int c = (w << 6) + j;            // uniform across the wave
        const float* up = uphi + c*ND;         // uniform address -> s_load
        const float u00=up[0], u01=up[1], u02=up[2],  u03=up[3];
        const float u04=up[4], u05=up[5], u06=up[6],  u07=up[7];
        const float u08=up[8], u09=up[9], u10=up[10], u11=up[11];
        const float u12=up[12],u13=up[13],u14=up[14], u15=up[15];
        const float mm = m[c];                 // uniform -> s_load
        const float d0 =
            a00.x*u00 + a00.y*u01 + a00.z*u02 + a00.w*u03 +
            a01.x*u04 + a01.y*u05 + a01.z*u06 + a01.w*u07 +
            a02.x*u08 + a02.y*u09 + a02.z*u10 + a02.w*u11 +
            a03.x*u12 + a03.y*u13 + a03.z*u14 + a03.w*u15;
        const float d1 =
            a10.x*u00 + a10.y*u01 + a10.z*u02 + a10.w*u03 +
            a11.x*u04 + a11.y*u05 + a11.z*u06 + a11.w*u07 +
            a12.x*u08 + a12.y*u09 + a12.z*u10 + a12.w*u11 +
            a13.x*u12 + a13.y*u13 + a13.z*u14 + a13.w*u15;
        denom0 += mm * __expf(d0);
        denom1 += mm * __expf(d1);
    }
    part_d[w][lane]      = denom0;
    part_d[w][64 + lane] = denom1;
    __syncthreads();

    // thread t < 128 finalizes pixel base + t (its own pp == w slot)
    float contrib = 0.f;
    if (t < 128) {
        const int seg = sam[base + t];
        const int cl = (seg > 0) ? (seg - 1) : 0;
        // select this thread's semantic registers (w is 0 or 1 here)
        float4 b0 = a00, b1 = a01, b2 = a02, b3 = a03;
        if (w == 1) { b0 = a10; b1 = a11; b2 = a12; b3 = a13; }
        const float4* uo = (const float4*)(uphi + cl*ND);   // divergent gather
        const float4 c0 = uo[0], c1 = uo[1], c2 = uo[2], c3 = uo[3];
        const float down =
            b0.x*c0.x + b0.y*c0.y + b0.z*c0.z + b0.w*c0.w +
            b1.x*c1.x + b1.y*c1.y + b1.z*c1.z + b1.w*c1.w +
            b2.x*c2.x + b2.y*c2.y + b2.z*c2.z + b2.w*c2.w +
            b3.x*c3.x + b3.y*c3.y + b3.z*c3.z + b3.w*c3.w;
        const float mo = m[cl];
        const float dtot = part_d[0][t] + part_d[1][t] + part_d[2][t] + part_d[3][t] + 1e-6f;
        contrib = (seg > 0 && mo > 0.5f) ? (__logf(dtot) - down) : 0.f;
    }
#pragma unroll
    for (int off = 32; off > 0; off >>= 1) contrib += __shfl_xor(contrib, off);
    if ((t & 63) == 0) red_s[t >> 6] = contrib;
    __syncthreads();
    if (t == 0) atomicAdd(&scal[2], red_s[0]+red_s[1]+red_s[2]+red_s[3]);

    // last-block finalize
    if (t == 0) {
        __threadfence();
        unsigned* done = (unsigned*)(scal + 3);
        const unsigned old = atomicAdd(done, 1u);
        if (old == gridDim.x - 1) {
            const float proto = atomicAdd(&scal[2], 0.f);
            const float nrm   = atomicAdd(&scal[0], 0.f);
            const float wsum  = atomicAdd(&scal[1], 0.f);
            o_sem[0] = 1e-4f * proto + 100.f * nrm / fmaxf(wsum, 1.f);
        }
    }
}

extern "C" void kernel_launch(void* const* d_in, const int* in_sizes, int n_in,
                              void* d_out, int out_size, void* d_ws, size_t ws_size,
                              hipStream_t stream)
{
    const float* rgb_pred = (const float*)d_in[0];
    const float* rgb_gt   = (const float*)d_in[1];
    const float* opacity  = (const float*)d_in[2];
    const float* wsv      = (const float*)d_in[3];
    const float* deltas   = (const float*)d_in[4];
    const float* tsv      = (const float*)d_in[5];
    const int*   rays_a   = (const int*)d_in[6];
    const int*   sam      = (const int*)d_in[7];
    const float* semantic = (const float*)d_in[8];

    float* out    = (float*)d_out;
    float* o_rgb  = out;                 // 196608
    float* o_opac = out + 196608;        // 65536
    float* o_dist = out + 262144;        // 65536
    float* o_sem  = out + 327680;        // 1
    float* wsf    = (float*)d_ws;

    // choose partial-block counts by available workspace (deterministic)
    int nblkA = 256, nblkC = 256;
    size_t need = ((size_t)nblkA*NC*(ND+1) + (size_t)nblkC*NC + NC*(2*ND+2) + 8) * 4;
    if (ws_size < need) { nblkA = 128; nblkC = 128; }
    const int ppbA = NPIX / (nblkA * 256);
    const int ppbC = NPIX / (nblkC * 256);

    float* w_cntpart = wsf;
    float* w_usum    = w_cntpart + (size_t)nblkA*NC;
    float* w_devpart = w_usum + (size_t)nblkA*NC*ND;
    float* w_cnt     = w_devpart + (size_t)nblkC*NC;
    float* w_u       = w_cnt + NC;
    float* w_uphi    = w_u + NC*ND;
    float* w_m       = w_uphi + NC*ND;
    float* w_scal    = w_m + NC;      // [0]=norm [1]=wsum [2]=proto [3]=done-counter

    hipMemsetAsync(w_scal, 0, 4*sizeof(float), stream);

    kFront<<<nblkA + DIST_BLOCKS, 256, 0, stream>>>(
        rgb_pred, rgb_gt, opacity, sam, semantic,
        wsv, deltas, tsv, rays_a,
        o_rgb, o_opac, o_dist,
        w_cntpart, w_usum, w_scal, nblkA, ppbA);
    kP1<<<NC, 256, 0, stream>>>(w_cntpart, w_usum, w_cnt, w_u, nblkA);
    kC<<<nblkC, 256, 0, stream>>>(semantic, sam, w_u, w_devpart, ppbC);
    kP2<<<NC, 256, 0, stream>>>(w_devpart, w_cnt, w_u, w_uphi, w_m, nblkC);
    kD<<<NPIX/128, 256, 0, stream>>>(semantic, sam, w_uphi, w_m, w_scal, o_sem);
}